// Round 11
// baseline (9721.637 us; speedup 1.0000x reference)
//
#include <hip/hip_runtime.h>

#define NN 100000
#define NE 3200000
#define DD 128
#define KC 10
#define NITER 10
#define NBK 1024
#define NTHR 256
#define NPAIR (NN / 2)
#define NE4 (NE / 4)
#define NSLOT 32  // barrier arrival counters (128B apart)

#define AG __HIP_MEMORY_SCOPE_AGENT

static __device__ __forceinline__ float agload(const float* p) {
  return __hip_atomic_load(p, __ATOMIC_RELAXED, AG);
}
static __device__ __forceinline__ void agstore(float* p, float v) {
  __hip_atomic_store(p, v, __ATOMIC_RELAXED, AG);
}

template <int CTRL, int RM>
__device__ __forceinline__ float dppadd(float v) {
  int t = __builtin_amdgcn_update_dpp(0, __builtin_bit_cast(int, v), CTRL, RM,
                                      0xF, true);
  return v + __builtin_bit_cast(float, t);
}
// After this: lane 31 holds sum of lanes 0..31, lane 63 holds sum of 32..63.
__device__ __forceinline__ float halfsum_tail(float v) {
  v = dppadd<0x111, 0xF>(v);
  v = dppadd<0x112, 0xF>(v);
  v = dppadd<0x114, 0xF>(v);
  v = dppadd<0x118, 0xF>(v);
  v = dppadd<0x142, 0xA>(v);
  return v;
}
__device__ __forceinline__ int bcast31i(int v) {
  return __builtin_amdgcn_ds_swizzle(v, 0x3E0);
}

// grid barrier: 32 padded arrival counters + go-flag at bar[NSLOT*32].
// All NBK blocks co-resident by construction (see launch_bounds arithmetic).
__device__ __forceinline__ void gsync(int* bar, int gen) {
  __syncthreads();
  __threadfence();
  if (threadIdx.x == 0) {
    const int slot = (blockIdx.x & (NSLOT - 1)) * 32;
    __hip_atomic_fetch_add(&bar[slot], 1, __ATOMIC_ACQ_REL, AG);
    if (blockIdx.x == 0) {
      for (int s = 0; s < NSLOT; ++s)
        while (__hip_atomic_load(&bar[s * 32], __ATOMIC_ACQUIRE, AG) <
               gen * (NBK / NSLOT))
          __builtin_amdgcn_s_sleep(2);
      __hip_atomic_store(&bar[NSLOT * 32], gen, __ATOMIC_RELEASE, AG);
    } else {
      while (__hip_atomic_load(&bar[NSLOT * 32], __ATOMIC_ACQUIRE, AG) < gen)
        __builtin_amdgcn_s_sleep(2);
    }
  }
  __syncthreads();
}

// ---- persistent kernel: 10x(assign+accumulate -> reduce) + qv + attention --
__global__ __launch_bounds__(NTHR, 4) void k_all(
    const float* __restrict__ x, const float* __restrict__ WQ,
    const float* __restrict__ WV, float* __restrict__ c,
    float* __restrict__ partial, float* __restrict__ cntpart,
    unsigned char* __restrict__ cl8, float* __restrict__ qv,
    float* __restrict__ CA, int* __restrict__ cnt, int* __restrict__ bar) {
  __shared__ float cs[KC][DD];
  __shared__ float wsum[4][KC][DD];
  __shared__ float wcnt[4][KC];
  __shared__ float pr[KC * KC];
  const int tid = threadIdx.x;
  const int w = tid >> 6, lane = tid & 63, half = lane >> 5, hl = lane & 31;
  const int gw = blockIdx.x * 4 + w;
  const float4* __restrict__ x4 = (const float4*)x;
  float* wsf = (float*)wsum;
  int gen = 0;

  for (int it = 0; it < NITER; ++it) {
    // ---- load centroids ----
    if (it == 0) {
      for (int i = tid; i < KC * DD; i += NTHR) ((float*)cs)[i] = x[i];
    } else {
      for (int i = tid; i < KC * DD; i += NTHR)
        ((float*)cs)[i] = agload(&c[i]);
    }
    for (int i = tid; i < 4 * KC * DD; i += NTHR) wsf[i] = 0.f;
    __syncthreads();

    float4 cfrag[KC];
    float bias[KC];
#pragma unroll
    for (int j = 0; j < KC; ++j) {
      const float4 c4 = *(const float4*)&cs[j][hl * 4];
      cfrag[j] = c4;
      bias[j] =
          -0.5f * (c4.x * c4.x + c4.y * c4.y + c4.z * c4.z + c4.w * c4.w);
    }
    float cntacc[KC];
#pragma unroll
    for (int j = 0; j < KC; ++j) cntacc[j] = 0.f;

    float* const wrow = &wsum[w][0][hl * 4];
    const int last = (it == NITER - 1);
    int p = gw;
    float4 v = x4[(size_t)(2 * p + half) * (DD / 4) + hl];
    for (; p < NPAIR; p += NBK * 4) {
      const int pn = p + NBK * 4;
      float4 vn = float4{0.f, 0.f, 0.f, 0.f};
      if (pn < NPAIR) vn = x4[(size_t)(2 * pn + half) * (DD / 4) + hl];

      float d[KC];
#pragma unroll
      for (int j = 0; j < KC; ++j)
        d[j] = bias[j] + v.x * cfrag[j].x + v.y * cfrag[j].y +
               v.z * cfrag[j].z + v.w * cfrag[j].w;
#pragma unroll
      for (int j = 0; j < KC; ++j) d[j] = halfsum_tail(d[j]);
      int best = 0;
      float bd = d[0];
#pragma unroll
      for (int j = 1; j < KC; ++j) {
        if (d[j] > bd) { bd = d[j]; best = j; }
      }
      const int bown = bcast31i(best);
      const int bother = __shfl_xor(bown, 32);
#pragma unroll
      for (int j = 0; j < KC; ++j)
        cntacc[j] += (bown == j && hl == 0) ? 1.f : 0.f;
      if (last && hl == 0) cl8[2 * p + half] = (unsigned char)bown;

      if (bown == bother) {
        float4 vs;
        vs.x = v.x + __shfl_xor(v.x, 32);
        vs.y = v.y + __shfl_xor(v.y, 32);
        vs.z = v.z + __shfl_xor(v.z, 32);
        vs.w = v.w + __shfl_xor(v.w, 32);
        if (half == 0) {
          float4 t = *(float4*)&wrow[bown * DD];
          t.x += vs.x; t.y += vs.y; t.z += vs.z; t.w += vs.w;
          *(float4*)&wrow[bown * DD] = t;
        }
      } else {
        float4 t = *(float4*)&wrow[bown * DD];
        t.x += v.x; t.y += v.y; t.z += v.z; t.w += v.w;
        *(float4*)&wrow[bown * DD] = t;
      }
      v = vn;
    }
    __syncthreads();
    for (int i = tid; i < KC * DD; i += NTHR)
      agstore(&partial[(size_t)blockIdx.x * (KC * DD) + i],
              wsf[i] + wsf[KC * DD + i] + wsf[2 * KC * DD + i] +
                  wsf[3 * KC * DD + i]);
#pragma unroll
    for (int j = 0; j < KC; ++j) cntacc[j] += __shfl_xor(cntacc[j], 32);
    if (half == 0 && hl == 0) {
#pragma unroll
      for (int j = 0; j < KC; ++j) wcnt[w][j] = cntacc[j];
    }
    __syncthreads();
    if (tid < KC)
      agstore(&cntpart[blockIdx.x * KC + tid],
              wcnt[0][tid] + wcnt[1][tid] + wcnt[2][tid] + wcnt[3][tid]);
    gsync(bar, ++gen);

    // ---- phase B: wave gw reduces column gw of partial (+ its count col) ---
    if (gw < KC * DD) {
      const int k = gw, j = k >> 7;
      float s = 0.f, sc = 0.f;
#pragma unroll
      for (int i = 0; i < NBK / 64; ++i) {
        s += agload(&partial[(size_t)(lane + 64 * i) * (KC * DD) + k]);
        sc += agload(&cntpart[(lane + 64 * i) * KC + j]);
      }
      s = halfsum_tail(s);
      s += __shfl_xor(s, 32);
      sc = halfsum_tail(sc);
      sc += __shfl_xor(sc, 32);
      if (lane == 63) agstore(&c[k], s / fmaxf(sc, 1.f));
    }
    gsync(bar, ++gen);
  }

  // ---- epilogue 1: qv (waves 0..39) ; cnt zeroing (blocks 10..1023) ----
  if (gw < 40) {
    // reload final centroids into LDS (blocks 0..9)
    for (int i = tid; i < KC * DD; i += NTHR) ((float*)cs)[i] = agload(&c[i]);
    __syncthreads();
    const int o = gw * 64 + lane;  // [0, 2560)
    const int mat = o / (KC * DD);
    const int rem = o - mat * (KC * DD);
    const int i = rem >> 7, k = rem & 127;
    const float* __restrict__ W = mat ? WV : WQ;
    float a = 0.f;
#pragma unroll 8
    for (int m = 0; m < DD; ++m) a += cs[i][m] * W[m * DD + k];
    agstore(&qv[o], a);
  } else if (blockIdx.x >= 10) {
    for (size_t i = tid + (size_t)(blockIdx.x - 10) * NTHR; i < (size_t)NN * KC;
         i += (size_t)(NBK - 10) * NTHR)
      cnt[i] = 0;
  }
  gsync(bar, ++gen);

  // ---- epilogue 2: 10x10 attention (block 0) ----
  if (blockIdx.x != 0) return;
  // reuse wsum as q/v staging: stride 132 to dodge bank conflicts
  float* qs = wsf;
  float* vs = wsf + KC * 132;
  for (int i = tid; i < KC * DD; i += NTHR) {
    const int r = i >> 7, k = i & 127;
    qs[r * 132 + k] = agload(&qv[i]);
    vs[r * 132 + k] = agload(&qv[KC * DD + i]);
  }
  __syncthreads();
  if (tid < KC * KC) {
    const int i = tid / KC, l = tid % KC;
    float a = 0.f;
#pragma unroll 8
    for (int m = 0; m < DD; ++m) a += qs[i * 132 + m] * vs[l * 132 + m];
    pr[tid] = a / sqrtf((float)DD);
  }
  __syncthreads();
  if (tid < KC) {
    float mx = pr[tid * KC];
    for (int l = 1; l < KC; ++l) mx = fmaxf(mx, pr[tid * KC + l]);
    float e[KC];
    float s = 0.f;
    for (int l = 0; l < KC; ++l) {
      e[l] = expf(pr[tid * KC + l] - mx);
      s += e[l];
    }
    for (int l = 0; l < KC; ++l) agstore(&CA[tid * KC + l], e[l] / s);
  }
}

// ------------- edge histogram -------------
__global__ __launch_bounds__(256) void k_cnt(const int* __restrict__ e0,
                                             const int* __restrict__ e1,
                                             const unsigned char* __restrict__ cl8,
                                             int* __restrict__ cnt) {
  const int i = blockIdx.x * 256 + threadIdx.x;  // [0, NE4)
  const int4 a = ((const int4*)e0)[i];
  const int4 b = ((const int4*)e1)[i];
  atomicAdd(&cnt[(size_t)a.x * KC + cl8[b.x]], 1);
  atomicAdd(&cnt[(size_t)a.y * KC + cl8[b.y]], 1);
  atomicAdd(&cnt[(size_t)a.z * KC + cl8[b.z]], 1);
  atomicAdd(&cnt[(size_t)a.w * KC + cl8[b.w]], 1);
}

// ------------- per-node denominator (row-max shift) -------------
__global__ __launch_bounds__(256) void k_tab2(
    const unsigned char* __restrict__ cl8, const int* __restrict__ cnt,
    const float* __restrict__ CA, float* __restrict__ den) {
  __shared__ float cas[KC * KC];
  __shared__ float rm[KC];
  if (threadIdx.x < KC * KC) cas[threadIdx.x] = CA[threadIdx.x];
  __syncthreads();
  if (threadIdx.x < KC) {
    float m = cas[threadIdx.x * KC];
    for (int l = 1; l < KC; ++l) m = fmaxf(m, cas[threadIdx.x * KC + l]);
    rm[threadIdx.x] = m;
  }
  __syncthreads();
  const int n = blockIdx.x * 256 + threadIdx.x;
  if (n >= NN) return;
  const int s = cl8[n];
  const float m = rm[s];
  float dsum = 0.f;
#pragma unroll
  for (int j = 0; j < KC; ++j) {
    const int cj = cnt[(size_t)n * KC + j];
    dsum += (float)cj * expf(cas[s * KC + j] - m);
  }
  den[n] = dsum;
}

// ------------- gather: out[e] = exp(ca - rm) / (den + eps) -------------
__global__ __launch_bounds__(256) void k_gather2(
    const int* __restrict__ e0, const int* __restrict__ e1,
    const unsigned char* __restrict__ cl8, const float* __restrict__ CA,
    const float* __restrict__ den, float* __restrict__ out) {
  __shared__ float cas[KC * KC];
  __shared__ float rm[KC];
  if (threadIdx.x < KC * KC) cas[threadIdx.x] = CA[threadIdx.x];
  __syncthreads();
  if (threadIdx.x < KC) {
    float m = cas[threadIdx.x * KC];
    for (int l = 1; l < KC; ++l) m = fmaxf(m, cas[threadIdx.x * KC + l]);
    rm[threadIdx.x] = m;
  }
  __syncthreads();
  const int i = blockIdx.x * 256 + threadIdx.x;  // [0, NE4)
  const int4 a = ((const int4*)e0)[i];
  const int4 b = ((const int4*)e1)[i];
  float4 r;
  {
    const int s = cl8[a.x];
    r.x = expf(cas[s * KC + cl8[b.x]] - rm[s]) / (den[a.x] + 1e-16f);
  }
  {
    const int s = cl8[a.y];
    r.y = expf(cas[s * KC + cl8[b.y]] - rm[s]) / (den[a.y] + 1e-16f);
  }
  {
    const int s = cl8[a.z];
    r.z = expf(cas[s * KC + cl8[b.z]] - rm[s]) / (den[a.z] + 1e-16f);
  }
  {
    const int s = cl8[a.w];
    r.w = expf(cas[s * KC + cl8[b.w]] - rm[s]) / (den[a.w] + 1e-16f);
  }
  ((float4*)out)[i] = r;
}

// ---------------- launch ----------------
extern "C" void kernel_launch(void* const* d_in, const int* in_sizes, int n_in,
                              void* d_out, int out_size, void* d_ws,
                              size_t ws_size, hipStream_t stream) {
  const float* x = (const float*)d_in[0];
  const int* edge = (const int*)d_in[1];
  const float* WQ = (const float*)d_in[2];
  const float* WV = (const float*)d_in[3];
  float* out = (float*)d_out;
  const int* e0 = edge;
  const int* e1 = edge + NE;

  float* ws = (float*)d_ws;
  float* c = ws;                                     // 1280
  float* CA = ws + 1280;                             // 112 (pad)
  float* qv = ws + 1392;                             // 2560
  float* den = qv + 2 * KC * DD;                     // NN
  float* partial = den + NN;                         // NBK*KC*DD
  float* cntpart = partial + (size_t)NBK * KC * DD;  // NBK*KC
  int* cnt = (int*)(cntpart + NBK * KC);             // NN*KC ints
  unsigned char* cl8 = (unsigned char*)(cnt + (size_t)NN * KC);  // NN bytes
  int* bar = (int*)(cl8 + ((NN + 255) & ~255));      // NSLOT*32+32 ints
  // total ~9.8 MB

  hipMemsetAsync(bar, 0, (NSLOT * 32 + 32) * sizeof(int), stream);

  k_all<<<NBK, NTHR, 0, stream>>>(x, WQ, WV, c, partial, cntpart, cl8, qv, CA,
                                  cnt, bar);
  k_cnt<<<NE4 / 256, 256, 0, stream>>>(e0, e1, cl8, cnt);
  k_tab2<<<(NN + 255) / 256, 256, 0, stream>>>(cl8, cnt, CA, den);
  k_gather2<<<NE4 / 256, 256, 0, stream>>>(e0, e1, cl8, CA, den, out);
}

// Round 12
// 858.972 us; speedup vs baseline: 11.3178x; 11.3178x over previous
//
#include <hip/hip_runtime.h>

#define NN 100000
#define NE 3200000
#define DD 128
#define KC 10
#define NITER 10
#define NBK 1024   // k_iter blocks = 4 per CU
#define NPAIR (NN / 2)
#define NE4 (NE / 4)

template <int CTRL, int RM>
__device__ __forceinline__ float dppadd(float v) {
  int t = __builtin_amdgcn_update_dpp(0, __builtin_bit_cast(int, v), CTRL, RM,
                                      0xF, true);
  return v + __builtin_bit_cast(float, t);
}

// After this: lane 31 holds sum of lanes 0..31, lane 63 holds sum of 32..63.
__device__ __forceinline__ float halfsum_tail(float v) {
  v = dppadd<0x111, 0xF>(v);  // row_shr:1
  v = dppadd<0x112, 0xF>(v);  // row_shr:2
  v = dppadd<0x114, 0xF>(v);  // row_shr:4
  v = dppadd<0x118, 0xF>(v);  // row_shr:8
  v = dppadd<0x142, 0xA>(v);  // row_bcast:15 into rows 1,3
  return v;
}
// broadcast lane 31 -> lanes 0..31 and lane 63 -> lanes 32..63
__device__ __forceinline__ int bcast31i(int v) {
  return __builtin_amdgcn_ds_swizzle(v, 0x3E0);
}

// ------------- fused assign + accumulate, half-wave per row ----------------
// NOTE: __launch_bounds__(256, 2) — (256,4) capped the allocator at 64 VGPRs
// and silently spilled the ~95-VGPR hot loop (R7/R11 evidence: VGPR=64 +
// 200-500MB scratch traffic). With min-waves=2 the allocator gets headroom.
__global__ __launch_bounds__(256, 2) void k_iter(
    const float* __restrict__ x, const float* __restrict__ csrc,
    float* __restrict__ partial, float* __restrict__ cntpart,
    unsigned char* __restrict__ cl8, int last) {
  __shared__ float cs[KC][DD];
  __shared__ float wsum[4][KC][DD];
  __shared__ float wcnt[4][KC];
  const int tid = threadIdx.x;
  float* wsf = (float*)wsum;
  for (int i = tid; i < KC * DD; i += 256) ((float*)cs)[i] = csrc[i];
  for (int i = tid; i < 4 * KC * DD; i += 256) wsf[i] = 0.f;
  __syncthreads();
  const int w = tid >> 6, lane = tid & 63, half = lane >> 5, hl = lane & 31;

  // per-lane centroid fragment + bias = -0.5*|c_frag|^2
  float4 cfrag[KC];
  float bias[KC];
#pragma unroll
  for (int j = 0; j < KC; ++j) {
    const float4 c4 = *(const float4*)&cs[j][hl * 4];
    cfrag[j] = c4;
    bias[j] = -0.5f * (c4.x * c4.x + c4.y * c4.y + c4.z * c4.z + c4.w * c4.w);
  }
  float cntacc[KC];
#pragma unroll
  for (int j = 0; j < KC; ++j) cntacc[j] = 0.f;

  float* const wrow = &wsum[w][0][hl * 4];  // base for this lane's RMW slots
  const float4* __restrict__ x4 = (const float4*)x;
  const int stride = NBK * 4;
  int p = blockIdx.x * 4 + w;
  // prefetch first pair
  float4 v = x4[(size_t)(2 * p + half) * (DD / 4) + hl];
  // score = dot(x,c) - 0.5|c|^2 ; argmax == argmin dist (strict >, first wins)
  for (; p < NPAIR; p += stride) {
    // issue next pair's load before computing on the current one
    const int pn = p + stride;
    float4 vn = float4{0.f, 0.f, 0.f, 0.f};
    if (pn < NPAIR) vn = x4[(size_t)(2 * pn + half) * (DD / 4) + hl];

    float d[KC];
#pragma unroll
    for (int j = 0; j < KC; ++j)
      d[j] = bias[j] + v.x * cfrag[j].x + v.y * cfrag[j].y + v.z * cfrag[j].z +
             v.w * cfrag[j].w;
#pragma unroll
    for (int j = 0; j < KC; ++j) d[j] = halfsum_tail(d[j]);
    int best = 0;  // meaningful in lanes 31/63 only
    float bd = d[0];
#pragma unroll
    for (int j = 1; j < KC; ++j) {
      if (d[j] > bd) { bd = d[j]; best = j; }
    }
    const int bown = bcast31i(best);          // own half's best (all lanes)
    const int bother = __shfl_xor(bown, 32);  // other half's best
#pragma unroll
    for (int j = 0; j < KC; ++j)
      cntacc[j] += (bown == j && hl == 0) ? 1.f : 0.f;
    if (last && hl == 0) cl8[2 * p + half] = (unsigned char)bown;

    if (bown == bother) {  // wave-uniform: both rows -> same centroid
      float4 vs;
      vs.x = v.x + __shfl_xor(v.x, 32);
      vs.y = v.y + __shfl_xor(v.y, 32);
      vs.z = v.z + __shfl_xor(v.z, 32);
      vs.w = v.w + __shfl_xor(v.w, 32);
      if (half == 0) {
        float4 t = *(float4*)&wrow[bown * DD];
        t.x += vs.x; t.y += vs.y; t.z += vs.z; t.w += vs.w;
        *(float4*)&wrow[bown * DD] = t;
      }
    } else {  // halves target different centroids: disjoint addresses
      float4 t = *(float4*)&wrow[bown * DD];
      t.x += v.x; t.y += v.y; t.z += v.z; t.w += v.w;
      *(float4*)&wrow[bown * DD] = t;
    }
    v = vn;
  }
  // counts: combine halves, flush
  __syncthreads();
  for (int i = tid; i < KC * DD; i += 256)
    partial[(size_t)blockIdx.x * (KC * DD) + i] =
        wsf[i] + wsf[KC * DD + i] + wsf[2 * KC * DD + i] + wsf[3 * KC * DD + i];
#pragma unroll
  for (int j = 0; j < KC; ++j) cntacc[j] += __shfl_xor(cntacc[j], 32);
  if (half == 0 && hl == 0) {
#pragma unroll
    for (int j = 0; j < KC; ++j) wcnt[w][j] = cntacc[j];
  }
  __syncthreads();
  if (tid < KC)
    cntpart[blockIdx.x * KC + tid] =
        wcnt[0][tid] + wcnt[1][tid] + wcnt[2][tid] + wcnt[3][tid];
}

// ------------- centroid update: block = (j, quarter of columns) -------------
__global__ __launch_bounds__(256) void k_update(
    const float* __restrict__ partial, const float* __restrict__ cntpart,
    float* __restrict__ c) {
  const int j = blockIdx.x >> 2, q = blockIdx.x & 3;  // <<<KC*4, 256>>>
  const int tid = threadIdx.x;
  __shared__ float creds[256];
  __shared__ float red[8][32];
  float cf = 0.f;
  for (int b = tid; b < NBK; b += 256) cf += cntpart[b * KC + j];
  creds[tid] = cf;
  __syncthreads();
  for (int s = 128; s > 0; s >>= 1) {
    if (tid < s) creds[tid] += creds[tid + s];
    __syncthreads();
  }
  const float denom = fmaxf(creds[0], 1.f);
  const int col = q * 32 + (tid & 31);
  const int r0 = tid >> 5;  // 0..7
  float s0 = 0.f;
  for (int b = r0; b < NBK; b += 8)
    s0 += partial[(size_t)b * (KC * DD) + j * DD + col];
  red[r0][tid & 31] = s0;
  __syncthreads();
  if (tid < 32) {
    float t = 0.f;
#pragma unroll
    for (int r = 0; r < 8; ++r) t += red[r][tid];
    c[j * DD + q * 32 + tid] = t / denom;
  }
}

// ------------- q/v projection: block = (mat, row i), 128 threads ------------
__global__ __launch_bounds__(DD) void k_qv(const float* __restrict__ c,
                                           const float* __restrict__ WQ,
                                           const float* __restrict__ WV,
                                           float* __restrict__ qv) {
  const int b = blockIdx.x;            // <<<2*KC, DD>>>
  const int mat = b / KC, i = b % KC;
  const float* __restrict__ W = mat ? WV : WQ;
  __shared__ float cr[DD];
  const int k = threadIdx.x;
  cr[k] = c[i * DD + k];
  __syncthreads();
  float a = 0.f;
#pragma unroll 8
  for (int m = 0; m < DD; ++m) a += cr[m] * W[m * DD + k];
  qv[(size_t)mat * KC * DD + i * DD + k] = a;
}

// ------------- 10x10 scores + row softmax -------------
__global__ __launch_bounds__(DD) void k_att(const float* __restrict__ qv,
                                            float* __restrict__ CA) {
  __shared__ float q[KC][DD + 2], v[KC][DD + 2], pr[KC][KC];
  const int tid = threadIdx.x;  // <<<1, DD>>>
  for (int i = 0; i < KC; ++i) {
    q[i][tid] = qv[i * DD + tid];
    v[i][tid] = qv[KC * DD + i * DD + tid];
  }
  __syncthreads();
  if (tid < KC * KC) {
    const int i = tid / KC, l = tid % KC;
    float acc = 0.f;
#pragma unroll 8
    for (int m = 0; m < DD; ++m) acc += q[i][m] * v[l][m];
    pr[i][l] = acc / sqrtf((float)DD);
  }
  __syncthreads();
  if (tid < KC) {
    float mx = pr[tid][0];
    for (int l = 1; l < KC; ++l) mx = fmaxf(mx, pr[tid][l]);
    float e[KC];
    float s = 0.f;
    for (int l = 0; l < KC; ++l) {
      e[l] = expf(pr[tid][l] - mx);
      s += e[l];
    }
    for (int l = 0; l < KC; ++l) CA[tid * KC + l] = e[l] / s;
  }
}

// ------------- edge histogram (two dispatches for profiler visibility) ------
__global__ __launch_bounds__(256) void k_cnt(const int* __restrict__ e0,
                                             const int* __restrict__ e1,
                                             const unsigned char* __restrict__ cl8,
                                             int* __restrict__ cnt, int base) {
  const int i = base + blockIdx.x * 256 + threadIdx.x;  // int4 index
  if (i >= NE4) return;
  const int4 a = ((const int4*)e0)[i];
  const int4 b = ((const int4*)e1)[i];
  atomicAdd(&cnt[(size_t)a.x * KC + cl8[b.x]], 1);
  atomicAdd(&cnt[(size_t)a.y * KC + cl8[b.y]], 1);
  atomicAdd(&cnt[(size_t)a.z * KC + cl8[b.z]], 1);
  atomicAdd(&cnt[(size_t)a.w * KC + cl8[b.w]], 1);
}

// ------------- per-node denominator (row-max shift) -------------
__global__ __launch_bounds__(256) void k_tab2(
    const unsigned char* __restrict__ cl8, const int* __restrict__ cnt,
    const float* __restrict__ CA, float* __restrict__ den) {
  __shared__ float cas[KC * KC];
  __shared__ float rm[KC];
  if (threadIdx.x < KC * KC) cas[threadIdx.x] = CA[threadIdx.x];
  __syncthreads();
  if (threadIdx.x < KC) {
    float m = cas[threadIdx.x * KC];
    for (int l = 1; l < KC; ++l) m = fmaxf(m, cas[threadIdx.x * KC + l]);
    rm[threadIdx.x] = m;
  }
  __syncthreads();
  const int n = blockIdx.x * 256 + threadIdx.x;
  if (n >= NN) return;
  const int s = cl8[n];
  const float m = rm[s];
  float dsum = 0.f;
#pragma unroll
  for (int j = 0; j < KC; ++j) {
    const int cj = cnt[(size_t)n * KC + j];
    dsum += (float)cj * expf(cas[s * KC + j] - m);
  }
  den[n] = dsum;
}

// ------------- gather: out[e] = exp(ca - rm) / (den + eps) -------------
__global__ __launch_bounds__(256) void k_gather2(
    const int* __restrict__ e0, const int* __restrict__ e1,
    const unsigned char* __restrict__ cl8, const float* __restrict__ CA,
    const float* __restrict__ den, float* __restrict__ out) {
  __shared__ float cas[KC * KC];
  __shared__ float rm[KC];
  if (threadIdx.x < KC * KC) cas[threadIdx.x] = CA[threadIdx.x];
  __syncthreads();
  if (threadIdx.x < KC) {
    float m = cas[threadIdx.x * KC];
    for (int l = 1; l < KC; ++l) m = fmaxf(m, cas[threadIdx.x * KC + l]);
    rm[threadIdx.x] = m;
  }
  __syncthreads();
  const int i = blockIdx.x * 256 + threadIdx.x;  // [0, NE4)
  const int4 a = ((const int4*)e0)[i];
  const int4 b = ((const int4*)e1)[i];
  float4 r;
  {
    const int s = cl8[a.x];
    r.x = expf(cas[s * KC + cl8[b.x]] - rm[s]) / (den[a.x] + 1e-16f);
  }
  {
    const int s = cl8[a.y];
    r.y = expf(cas[s * KC + cl8[b.y]] - rm[s]) / (den[a.y] + 1e-16f);
  }
  {
    const int s = cl8[a.z];
    r.z = expf(cas[s * KC + cl8[b.z]] - rm[s]) / (den[a.z] + 1e-16f);
  }
  {
    const int s = cl8[a.w];
    r.w = expf(cas[s * KC + cl8[b.w]] - rm[s]) / (den[a.w] + 1e-16f);
  }
  ((float4*)out)[i] = r;
}

// ---------------- launch ----------------
extern "C" void kernel_launch(void* const* d_in, const int* in_sizes, int n_in,
                              void* d_out, int out_size, void* d_ws,
                              size_t ws_size, hipStream_t stream) {
  const float* x = (const float*)d_in[0];
  const int* edge = (const int*)d_in[1];
  const float* WQ = (const float*)d_in[2];
  const float* WV = (const float*)d_in[3];
  float* out = (float*)d_out;
  const int* e0 = edge;
  const int* e1 = edge + NE;

  float* ws = (float*)d_ws;
  float* c = ws;                                     // 1280
  float* CA = ws + 1280;                             // 112 (pad)
  float* qv = ws + 1392;                             // 2*1280 = 2560
  float* den = qv + 2 * KC * DD;                     // NN
  float* partial = den + NN;                         // NBK*KC*DD = 1,310,720
  float* cntpart = partial + (size_t)NBK * KC * DD;  // NBK*KC = 10240
  int* cnt = (int*)(cntpart + NBK * KC);             // NN*KC ints
  unsigned char* cl8 = (unsigned char*)(cnt + (size_t)NN * KC);  // NN bytes
  // total ~9.8 MB

  hipMemsetAsync(cnt, 0, (size_t)NN * KC * sizeof(int), stream);

  for (int it = 0; it < NITER; ++it) {
    const float* csrc = (it == 0) ? x : c;
    k_iter<<<NBK, 256, 0, stream>>>(x, csrc, partial, cntpart, cl8,
                                    it == NITER - 1);
    k_update<<<KC * 4, 256, 0, stream>>>(partial, cntpart, c);
  }
  k_qv<<<2 * KC, DD, 0, stream>>>(c, WQ, WV, qv);
  k_att<<<1, DD, 0, stream>>>(qv, CA);
  const int HALF_BLKS = 1563;  // NE4 = 800000 = 3125 blocks of 256
  k_cnt<<<HALF_BLKS, 256, 0, stream>>>(e0, e1, cl8, cnt, 0);
  k_cnt<<<3125 - HALF_BLKS, 256, 0, stream>>>(e0, e1, cl8, cnt,
                                              HALF_BLKS * 256);
  k_tab2<<<(NN + 255) / 256, 256, 0, stream>>>(cl8, cnt, CA, den);
  k_gather2<<<NE4 / 256, 256, 0, stream>>>(e0, e1, cl8, CA, den, out);
}